// Round 4
// baseline (302.615 us; speedup 1.0000x reference)
//
#include <hip/hip_runtime.h>

#define B_    2
#define S_    2048
#define H_    32
#define KVH_  8
#define D_    128
#define QB    128
#define NT_   (S_ / 64)      // 64-key prep tiles = 32
#define SCALE2 0.12751743f   // 128^-0.5 * log2(e): softmax in log2 domain (folded into Q)
#define THR2  8.0f           // defer-max threshold (log2 units)

typedef short  short8 __attribute__((ext_vector_type(8)));
typedef float  f32x4  __attribute__((ext_vector_type(4)));

__device__ inline unsigned short f2bf(float f) {
    unsigned int u = __float_as_uint(f);
    u += 0x7fffu + ((u >> 16) & 1u);
    return (unsigned short)(u >> 16);
}
__device__ __forceinline__ float exp2_fast(float x) {   // v_exp_f32 = 2^x
    float r; asm("v_exp_f32 %0, %1" : "=v"(r) : "v"(x)); return r;
}
__device__ __forceinline__ unsigned int cvt_pk_bf16(float lo, float hi) {
    unsigned int r;
    asm("v_cvt_pk_bf16_f32 %0, %1, %2" : "=v"(r) : "v"(lo), "v"(hi));
    return r;
}

// ---- prepass: MFMA-fragment-ordered bf16 K and V (same output layout, 2x blocks) ----
__global__ void prep_kernel(const float* __restrict__ k, const float* __restrict__ v,
                            unsigned short* __restrict__ kfb,
                            unsigned short* __restrict__ vfb) {
    __shared__ unsigned short Kt[32][136];
    __shared__ unsigned short Vt[32][132];
    const int t = threadIdx.x;
    const int kt64 = blockIdx.x >> 1, sub = blockIdx.x & 1;
    const int bkvh = blockIdx.y;
    const int b = bkvh >> 3, kvh = bkvh & 7;
    const size_t rs = KVH_ * D_;
    const float* ks = k + ((size_t)(b * S_ + kt64 * 64 + sub * 32)) * rs + kvh * D_;
    const float* vs = v + ((size_t)(b * S_ + kt64 * 64 + sub * 32)) * rs + kvh * D_;
    #pragma unroll
    for (int i = 0; i < 4; ++i) {
        const int row = (t >> 5) + i * 8;
        const int col = (t & 31) * 4;
        const float4 a = *(const float4*)(ks + (size_t)row * rs + col);
        const float4 c = *(const float4*)(vs + (size_t)row * rs + col);
        ushort4 wa, wc;
        wa.x = f2bf(a.x); wa.y = f2bf(a.y); wa.z = f2bf(a.z); wa.w = f2bf(a.w);
        wc.x = f2bf(c.x); wc.y = f2bf(c.y); wc.z = f2bf(c.z); wc.w = f2bf(c.w);
        *(ushort4*)&Kt[row][col] = wa;
        *(ushort4*)&Vt[row][col] = wc;
    }
    __syncthreads();
    const int lane = t & 63, m16 = lane & 15, quad = lane >> 4;
    const int w = t >> 6;
    unsigned short* kout = kfb + (size_t)(bkvh * NT_ + kt64) * 16 * 512;
    unsigned short* vout = vfb + (size_t)(bkvh * NT_ + kt64) * 16 * 512;
    #pragma unroll
    for (int ntl = 0; ntl < 2; ++ntl) {
        const short8 kk = *(const short8*)&Kt[ntl * 16 + m16][w * 32 + quad * 8];
        *(short8*)(kout + (w * 4 + sub * 2 + ntl) * 512 + lane * 8) = kk;
    }
    #pragma unroll
    for (int i = 0; i < 2; ++i) {
        const int dn = w * 2 + i;
        short8 vv;
        #pragma unroll
        for (int j = 0; j < 8; ++j)
            vv[j] = (short)Vt[quad * 8 + j][dn * 16 + m16];
        *(short8*)(vout + (sub * 8 + dn) * 512 + lane * 8) = vv;
    }
}

// ---- fa10: 4 waves x 32 q-rows (2 row-blocks), KB=32 tiles, 3 blocks/CU ----
#define TILE64_B 16384
#define BUF_B    16384
#define PSH_OFF  32768
#define SMEM_B   (PSH_OFF + 128 * 64 * 2)   // 49152 B -> 3 blocks/CU

__device__ __forceinline__ void gld16(const void* g, void* l) {
    __builtin_amdgcn_global_load_lds(
        (const __attribute__((address_space(1))) unsigned int*)g,
        (__attribute__((address_space(3))) unsigned int*)l, 16, 0, 0);
}

__global__ __launch_bounds__(256, 3) void fa10_kernel(
    const float* __restrict__ q, const unsigned short* __restrict__ kfb,
    const unsigned short* __restrict__ vfb, float* __restrict__ out) {

    __shared__ __align__(16) char smem[SMEM_B];
    unsigned short* Psh = (unsigned short*)(smem + PSH_OFF);

    const int t    = threadIdx.x;
    const int wave = t >> 6;
    const int lane = t & 63;
    const int m16  = lane & 15;
    const int quad = lane >> 4;

    const int qtile = 15 - (int)blockIdx.x;   // heavy qtiles dispatched first
    const int qbase = qtile * QB;
    const int ktmax = 4 * qtile + 3;

    const int bh  = blockIdx.y;
    const int b   = bh >> 5;
    const int h   = bh & 31;
    const int kvh = h >> 2;

    const char* kB = (const char*)kfb + (size_t)(b * KVH_ + kvh) * NT_ * TILE64_B;
    const char* vB = (const char*)vfb + (size_t)(b * KVH_ + kvh) * NT_ * TILE64_B;

    const int inner = lane * 16;
    const int g0 = wave;
    const int kst0 = ((g0 >> 1) * 4 + (g0 & 1)) * 1024 + inner;
    const int kst1 = (((g0 + 4) >> 1) * 4 + ((g0 + 4) & 1)) * 1024 + inner;

    const int psh_row0 = (wave * 16 + m16) * 64;
    unsigned short* pw0 = Psh + psh_row0 + ((((quad >> 1))     ^ (m16 & 7)) << 3) + (quad & 1) * 4;
    unsigned short* pw1 = Psh + psh_row0 + (((2 + (quad >> 1)) ^ (m16 & 7)) << 3) + (quad & 1) * 4;
    const unsigned short* pr = Psh + psh_row0 + ((quad ^ (m16 & 7)) << 3);

    // ---- stage tile 0 -> buf0 ----
    gld16(kB + kst0,          smem + t * 16);
    gld16(kB + kst1,          smem + 4096 + t * 16);
    gld16(vB + t * 16,        smem + 8192 + t * 16);
    gld16(vB + 4096 + t * 16, smem + 12288 + t * 16);

    // ---- Q A-fragments for both row-blocks, pre-scaled ----
    const int qr0 = qbase + wave * 16 + m16;
    const int qr1 = qr0 + 64;
    short8 qf[2][4];
    #pragma unroll
    for (int rb = 0; rb < 2; ++rb) {
        const float* qp = q + (size_t)(b * S_ + (rb ? qr1 : qr0)) * (H_ * D_) + h * D_;
        #pragma unroll
        for (int c = 0; c < 4; ++c) {
            const float4 x0 = *(const float4*)(qp + c * 32 + quad * 8);
            const float4 x1 = *(const float4*)(qp + c * 32 + quad * 8 + 4);
            short8 f;
            f[0] = (short)f2bf(x0.x * SCALE2); f[1] = (short)f2bf(x0.y * SCALE2);
            f[2] = (short)f2bf(x0.z * SCALE2); f[3] = (short)f2bf(x0.w * SCALE2);
            f[4] = (short)f2bf(x1.x * SCALE2); f[5] = (short)f2bf(x1.y * SCALE2);
            f[6] = (short)f2bf(x1.z * SCALE2); f[7] = (short)f2bf(x1.w * SCALE2);
            qf[rb][c] = f;
        }
    }

    f32x4 o[2][8];
    #pragma unroll
    for (int rb = 0; rb < 2; ++rb)
        #pragma unroll
        for (int i = 0; i < 8; ++i) o[rb][i] = (f32x4){0.f, 0.f, 0.f, 0.f};
    float m_q[2] = {-INFINITY, -INFINITY}, l_q[2] = {0.f, 0.f};

    __syncthreads();

    for (int ktt = 0; ktt <= ktmax; ++ktt) {
        const int kb  = ktt * 32;
        const int cur = ktt & 1;

        if (ktt < ktmax) {
            const int n = ktt + 1;
            const char* kt_ = kB + (size_t)(n >> 1) * TILE64_B + (n & 1) * 2048;
            const char* vt_ = vB + (size_t)(n >> 1) * TILE64_B + (n & 1) * 8192;
            char* dst = smem + (n & 1) * BUF_B;
            gld16(kt_ + kst0,          dst + t * 16);
            gld16(kt_ + kst1,          dst + 4096 + t * 16);
            gld16(vt_ + t * 16,        dst + 8192 + t * 16);
            gld16(vt_ + 4096 + t * 16, dst + 12288 + t * 16);
        }
        const unsigned short* Kl = (const unsigned short*)(smem + cur * BUF_B);
        const unsigned short* Vl = Kl + 4096;

        // ---- S^T = K Q^T for both row-blocks; K frags read once, used twice ----
        f32x4 sa[2][2];
        #pragma unroll
        for (int rb = 0; rb < 2; ++rb)
            #pragma unroll
            for (int ntl = 0; ntl < 2; ++ntl) sa[rb][ntl] = (f32x4){0.f, 0.f, 0.f, 0.f};
        __builtin_amdgcn_s_setprio(1);
        #pragma unroll
        for (int c = 0; c < 4; ++c) {
            const short8 kf0 = *(const short8*)(Kl + (c * 2)     * 512 + lane * 8);
            const short8 kf1 = *(const short8*)(Kl + (c * 2 + 1) * 512 + lane * 8);
            sa[0][0] = __builtin_amdgcn_mfma_f32_16x16x32_bf16(kf0, qf[0][c], sa[0][0], 0, 0, 0);
            sa[0][1] = __builtin_amdgcn_mfma_f32_16x16x32_bf16(kf1, qf[0][c], sa[0][1], 0, 0, 0);
            sa[1][0] = __builtin_amdgcn_mfma_f32_16x16x32_bf16(kf0, qf[1][c], sa[1][0], 0, 0, 0);
            sa[1][1] = __builtin_amdgcn_mfma_f32_16x16x32_bf16(kf1, qf[1][c], sa[1][1], 0, 0, 0);
        }
        __builtin_amdgcn_s_setprio(0);

        // ---- per-lane softmax per row-block ----
        #pragma unroll
        for (int rb = 0; rb < 2; ++rb) {
            const bool dodiag = (ktt >= 4 * qtile + 2 * rb);
            const int  qr = rb ? qr1 : qr0;
            float p[2][4];
            #pragma unroll
            for (int ntl = 0; ntl < 2; ++ntl) {
                #pragma unroll
                for (int r = 0; r < 4; ++r) {
                    float sv = sa[rb][ntl][r];
                    if (dodiag) {
                        const int keyg = kb + ntl * 16 + quad * 4 + r;
                        if (keyg > qr) sv = -INFINITY;
                    }
                    p[ntl][r] = sv;
                }
            }
            float mv;
            {
                const float t0 = fmaxf(fmaxf(p[0][0], p[0][1]), fmaxf(p[0][2], p[0][3]));
                const float t1 = fmaxf(fmaxf(p[1][0], p[1][1]), fmaxf(p[1][2], p[1][3]));
                mv = fmaxf(t0, t1);
                mv = fmaxf(mv, __shfl_xor(mv, 16));
                mv = fmaxf(mv, __shfl_xor(mv, 32));
            }
            if (__any(mv - m_q[rb] > THR2)) {
                const float mnew = fmaxf(m_q[rb], mv);
                const float al = exp2_fast(m_q[rb] - mnew);
                m_q[rb] = mnew;
                l_q[rb] *= al;
                float alo[4];
                #pragma unroll
                for (int r = 0; r < 4; ++r)
                    alo[r] = __shfl(al, quad * 20 + r);
                #pragma unroll
                for (int dn = 0; dn < 8; ++dn)
                    #pragma unroll
                    for (int r = 0; r < 4; ++r) o[rb][dn][r] *= alo[r];
            }
            {
                const float e0 = exp2_fast(p[0][0] - m_q[rb]);
                const float e1 = exp2_fast(p[0][1] - m_q[rb]);
                const float e2 = exp2_fast(p[0][2] - m_q[rb]);
                const float e3 = exp2_fast(p[0][3] - m_q[rb]);
                const float f0 = exp2_fast(p[1][0] - m_q[rb]);
                const float f1 = exp2_fast(p[1][1] - m_q[rb]);
                const float f2 = exp2_fast(p[1][2] - m_q[rb]);
                const float f3 = exp2_fast(p[1][3] - m_q[rb]);
                l_q[rb] += ((e0 + e1) + (e2 + e3)) + ((f0 + f1) + (f2 + f3));
                uint2 w0, w1;
                w0.x = cvt_pk_bf16(e0, e1); w0.y = cvt_pk_bf16(e2, e3);
                w1.x = cvt_pk_bf16(f0, f1); w1.y = cvt_pk_bf16(f2, f3);
                *(uint2*)(pw0 + rb * 4096) = w0;
                *(uint2*)(pw1 + rb * 4096) = w1;
            }
        }

        asm volatile("s_waitcnt lgkmcnt(0)" ::: "memory");
        short8 pf[2];
        pf[0] = *(const short8*)pr;
        pf[1] = *(const short8*)(pr + 4096);

        __builtin_amdgcn_s_setprio(1);
        #pragma unroll
        for (int dn = 0; dn < 8; ++dn) {
            const short8 vv = *(const short8*)(Vl + dn * 512 + lane * 8);
            o[0][dn] = __builtin_amdgcn_mfma_f32_16x16x32_bf16(pf[0], vv, o[0][dn], 0, 0, 0);
            o[1][dn] = __builtin_amdgcn_mfma_f32_16x16x32_bf16(pf[1], vv, o[1][dn], 0, 0, 0);
        }
        __builtin_amdgcn_s_setprio(0);

        __syncthreads();
    }

    // ---- epilogue ----
    float* Ot = (float*)smem + wave * 2048;
    #pragma unroll
    for (int rb = 0; rb < 2; ++rb) {
        float ls = l_q[rb];
        ls += __shfl_xor(ls, 16);
        ls += __shfl_xor(ls, 32);
        const float inv_q = 1.f / ls;
        float inv[4];
        #pragma unroll
        for (int r = 0; r < 4; ++r)
            inv[r] = __shfl(inv_q, quad * 20 + r);
        #pragma unroll
        for (int dn = 0; dn < 8; ++dn)
            #pragma unroll
            for (int r = 0; r < 4; ++r)
                Ot[(quad * 4 + r) * 128 + dn * 16 + m16] = o[rb][dn][r] * inv[r];
        asm volatile("s_waitcnt lgkmcnt(0)" ::: "memory");
        float* og = out + (size_t)(b * S_ + qbase + rb * 64 + wave * 16) * (H_ * D_) + h * D_;
        #pragma unroll
        for (int i = 0; i < 8; ++i) {
            const int row = (lane >> 5) + i * 2;
            const int col = (lane & 31) * 4;
            *(float4*)(og + (size_t)row * (H_ * D_) + col) = *(const float4*)(Ot + row * 128 + col);
        }
    }
}

extern "C" void kernel_launch(void* const* d_in, const int* in_sizes, int n_in,
                              void* d_out, int out_size, void* d_ws, size_t ws_size,
                              hipStream_t stream) {
    const float* q = (const float*)d_in[0];
    const float* k = (const float*)d_in[1];
    const float* v = (const float*)d_in[2];
    float* out = (float*)d_out;

    unsigned short* kfb = (unsigned short*)d_ws;                                  // 8 MB
    unsigned short* vfb = (unsigned short*)d_ws + (size_t)B_ * KVH_ * S_ * D_;    // 8 MB

    prep_kernel<<<dim3(NT_ * 2, B_ * KVH_), dim3(256), 0, stream>>>(k, v, kfb, vfb);
    fa10_kernel<<<dim3(16, B_ * H_), dim3(256), 0, stream>>>(q, kfb, vfb, out);
}

// Round 5
// 226.351 us; speedup vs baseline: 1.3369x; 1.3369x over previous
//
#include <hip/hip_runtime.h>

#define B_    2
#define S_    2048
#define H_    32
#define KVH_  8
#define D_    128
#define QB    128
#define NT_   (S_ / 64)      // 64-key tiles = 32
#define SCALE2 0.12751743f   // 128^-0.5 * log2(e): softmax in log2 domain (folded into Q)
#define THR2  8.0f           // defer-max threshold (log2 units)

typedef short  short8 __attribute__((ext_vector_type(8)));
typedef float  f32x4  __attribute__((ext_vector_type(4)));

__device__ inline unsigned short f2bf(float f) {
    unsigned int u = __float_as_uint(f);
    u += 0x7fffu + ((u >> 16) & 1u);
    return (unsigned short)(u >> 16);
}
__device__ __forceinline__ float exp2_fast(float x) {   // v_exp_f32 = 2^x
    float r; asm("v_exp_f32 %0, %1" : "=v"(r) : "v"(x)); return r;
}
__device__ __forceinline__ unsigned int cvt_pk_bf16(float lo, float hi) {
    unsigned int r;
    asm("v_cvt_pk_bf16_f32 %0, %1, %2" : "=v"(r) : "v"(lo), "v"(hi));
    return r;
}

// ---- prepass: MFMA-fragment-ordered bf16 K and V (fa9 verbatim, verified) ----
// kfb[(bkvh*NT+kt)*16 + (c*4+nt)][lane]  : K[key=kt*64+nt*16+m16][d=c*32+quad*8+j]
// vfb[(bkvh*NT+kt)*16 + (c2*8+dn)][lane] : V[key=kt*64+c2*32+quad*8+j][d=dn*16+m16]
__global__ void prep_kernel(const float* __restrict__ k, const float* __restrict__ v,
                            unsigned short* __restrict__ kfb,
                            unsigned short* __restrict__ vfb) {
    __shared__ unsigned short Kt[64][136];
    __shared__ unsigned short Vt[64][132];
    const int t = threadIdx.x;
    const int kt = blockIdx.x, bkvh = blockIdx.y;
    const int b = bkvh >> 3, kvh = bkvh & 7;
    const size_t rs = KVH_ * D_;
    const float* ks = k + ((size_t)(b * S_ + kt * 64)) * rs + kvh * D_;
    const float* vs = v + ((size_t)(b * S_ + kt * 64)) * rs + kvh * D_;
    #pragma unroll
    for (int i = 0; i < 8; ++i) {
        const int row = (t >> 5) + i * 8;
        const int col = (t & 31) * 4;
        const float4 a = *(const float4*)(ks + (size_t)row * rs + col);
        const float4 c = *(const float4*)(vs + (size_t)row * rs + col);
        ushort4 wa, wc;
        wa.x = f2bf(a.x); wa.y = f2bf(a.y); wa.z = f2bf(a.z); wa.w = f2bf(a.w);
        wc.x = f2bf(c.x); wc.y = f2bf(c.y); wc.z = f2bf(c.z); wc.w = f2bf(c.w);
        *(ushort4*)&Kt[row][col] = wa;
        *(ushort4*)&Vt[row][col] = wc;
    }
    __syncthreads();
    const int lane = t & 63, m16 = lane & 15, quad = lane >> 4;
    unsigned short* kout = kfb + (size_t)(bkvh * NT_ + kt) * 16 * 512;
    unsigned short* vout = vfb + (size_t)(bkvh * NT_ + kt) * 16 * 512;
    #pragma unroll
    for (int i = 0; i < 4; ++i) {
        const int g = (t >> 6) * 4 + i;          // 0..15
        const int c = g >> 2, nt = g & 3;
        const short8 kk = *(const short8*)&Kt[nt * 16 + m16][c * 32 + quad * 8];
        *(short8*)(kout + g * 512 + lane * 8) = kk;
        const int c2 = g >> 3, dn = g & 7;
        short8 vv;
        #pragma unroll
        for (int j = 0; j < 8; ++j)
            vv[j] = (short)Vt[c2 * 32 + quad * 8 + j][dn * 16 + m16];
        *(short8*)(vout + g * 512 + lane * 8) = vv;
    }
}

// ---- fa11: fa9 schedule (KB=64, 34 paired iters, 2 blocks/CU) + fa10 reuse ----
// 4 waves x 32 q-rows (rb0: wave*16, rb1: 64+wave*16); every K/V frag read once,
// feeds 2 MFMAs. LDS: buf0 [0,32K) buf1 [32K,64K) (K 16K + V 16K each);
// Psh [64K,80K): 128 rows x 64 shorts (rb*64 + wave*16 + m16), XOR-swizzled.
// Epilogue fp32 slab 4x[16][128] (32KB) aliases buf region after final barrier.
#define TILE_B  16384
#define BUF_B   32768
#define PSH_OFF 65536
#define SMEM_B  (PSH_OFF + 128 * 64 * 2)   // 81920 -> exactly 2 blocks/CU

__device__ __forceinline__ void gld16(const void* g, void* l) {
    __builtin_amdgcn_global_load_lds(
        (const __attribute__((address_space(1))) unsigned int*)g,
        (__attribute__((address_space(3))) unsigned int*)l, 16, 0, 0);
}

__global__ __launch_bounds__(256, 2) void fa11_kernel(
    const float* __restrict__ q, const unsigned short* __restrict__ kfb,
    const unsigned short* __restrict__ vfb, float* __restrict__ out) {

    __shared__ __align__(16) char smem[SMEM_B];
    unsigned short* Psh = (unsigned short*)(smem + PSH_OFF);

    const int t    = threadIdx.x;
    const int wave = t >> 6;          // 0..3, owns 32 q-rows (two 16-row sub-blocks)
    const int lane = t & 63;
    const int m16  = lane & 15;       // lane's q-row within its 16-row group (swapped layout)
    const int quad = lane >> 4;

    const int bh  = blockIdx.y;
    const int b   = bh >> 5;
    const int h   = bh & 31;
    const int kvh = h >> 2;

    const char* kB = (const char*)kfb + (size_t)(b * KVH_ + kvh) * NT_ * TILE_B;
    const char* vB = (const char*)vfb + (size_t)(b * KVH_ + kvh) * NT_ * TILE_B;

    // Psh addressing (fa9/fa10-verified swizzle, rb region at +4096 shorts):
    // write col = nt*16+quad*4+r (b64, 2 cvt_pk); blk = (col>>3) ^ (m16&7)
    // read  col = c2*32+quad*8  (b128);           blk = (col>>3) ^ (m16&7)
    const int psh_row = (wave * 16 + m16) * 64;
    unsigned short* pw[4];
    #pragma unroll
    for (int nt = 0; nt < 4; ++nt)
        pw[nt] = Psh + psh_row + (((nt * 2 + (quad >> 1)) ^ (m16 & 7)) << 3) + (quad & 1) * 4;
    const unsigned short* pr0 = Psh + psh_row + (((quad)     ^ (m16 & 7)) << 3);
    const unsigned short* pr1 = Psh + psh_row + (((4 + quad) ^ (m16 & 7)) << 3);

    // causal pairing: qtile (15-bx) then (bx) -> every block does exactly 34 k-tile iters
    for (int half = 0; half < 2; ++half) {
        const int qtile = half ? (int)blockIdx.x : (15 - (int)blockIdx.x);
        const int qbase = qtile * QB;
        const int ktmax = 2 * qtile + 1;

        if (half) __syncthreads();   // epilogue slab reads of half 0 done before restaging buf0

        // ---- stage tile 0 -> buf0 (K 16KB + V 16KB; 256 thr x 16B x 4 rounds each) ----
        #pragma unroll
        for (int r = 0; r < 4; ++r) {
            gld16(kB + r * 4096 + t * 16, smem + r * 4096 + t * 16);
            gld16(vB + r * 4096 + t * 16, smem + 16384 + r * 4096 + t * 16);
        }

        // ---- Q A-fragments for both sub-blocks, pre-scaled by SCALE2 ----
        const int qr0 = qbase + wave * 16 + m16;
        const int qr1 = qr0 + 64;
        short8 qf[2][4];
        #pragma unroll
        for (int rb = 0; rb < 2; ++rb) {
            const float* qp = q + (size_t)(b * S_ + (rb ? qr1 : qr0)) * (H_ * D_) + h * D_;
            #pragma unroll
            for (int c = 0; c < 4; ++c) {
                const float4 x0 = *(const float4*)(qp + c * 32 + quad * 8);
                const float4 x1 = *(const float4*)(qp + c * 32 + quad * 8 + 4);
                short8 f;
                f[0] = (short)f2bf(x0.x * SCALE2); f[1] = (short)f2bf(x0.y * SCALE2);
                f[2] = (short)f2bf(x0.z * SCALE2); f[3] = (short)f2bf(x0.w * SCALE2);
                f[4] = (short)f2bf(x1.x * SCALE2); f[5] = (short)f2bf(x1.y * SCALE2);
                f[6] = (short)f2bf(x1.z * SCALE2); f[7] = (short)f2bf(x1.w * SCALE2);
                qf[rb][c] = f;
            }
        }

        f32x4 o[2][8];
        #pragma unroll
        for (int rb = 0; rb < 2; ++rb)
            #pragma unroll
            for (int i = 0; i < 8; ++i) o[rb][i] = (f32x4){0.f, 0.f, 0.f, 0.f};
        float m_q[2] = {-INFINITY, -INFINITY}, l_q[2] = {0.f, 0.f};

        __syncthreads();   // tile 0 staged (vmcnt drained) and visible

        for (int ktt = 0; ktt <= ktmax; ++ktt) {
            const int kb  = ktt * 64;
            const int cur = ktt & 1;

            // ---- issue next tile's staging; flies under this tile's compute ----
            if (ktt < ktmax) {
                const char* ks = kB + (size_t)(ktt + 1) * TILE_B + t * 16;
                const char* vs = vB + (size_t)(ktt + 1) * TILE_B + t * 16;
                char* dst = smem + (cur ^ 1) * BUF_B + t * 16;
                #pragma unroll
                for (int r = 0; r < 4; ++r) {
                    gld16(ks + r * 4096, dst + r * 4096);
                    gld16(vs + r * 4096, dst + 16384 + r * 4096);
                }
            }
            const unsigned short* Kl = (const unsigned short*)(smem + cur * BUF_B);
            const unsigned short* Vl = Kl + 8192;   // +16384 B

            // ---- S^T = K Q^T for both sub-blocks; each K frag read once, 2 MFMAs ----
            f32x4 sa[2][4];
            #pragma unroll
            for (int rb = 0; rb < 2; ++rb)
                #pragma unroll
                for (int nt = 0; nt < 4; ++nt) sa[rb][nt] = (f32x4){0.f, 0.f, 0.f, 0.f};
            __builtin_amdgcn_s_setprio(1);
            #pragma unroll
            for (int c = 0; c < 4; ++c) {
                short8 kf[4];
                #pragma unroll
                for (int nt = 0; nt < 4; ++nt)
                    kf[nt] = *(const short8*)(Kl + (c * 4 + nt) * 512 + lane * 8);
                #pragma unroll
                for (int nt = 0; nt < 4; ++nt) {
                    sa[0][nt] = __builtin_amdgcn_mfma_f32_16x16x32_bf16(kf[nt], qf[0][c], sa[0][nt], 0, 0, 0);
                    sa[1][nt] = __builtin_amdgcn_mfma_f32_16x16x32_bf16(kf[nt], qf[1][c], sa[1][nt], 0, 0, 0);
                }
            }
            __builtin_amdgcn_s_setprio(0);

            // ---- per-lane softmax per sub-block (lane owns q-row m16; 16 keys/lane) ----
            #pragma unroll
            for (int rb = 0; rb < 2; ++rb) {
                const bool dodiag = (ktt >= 2 * qtile + rb);
                const int  qr = rb ? qr1 : qr0;
                float p[4][4];
                #pragma unroll
                for (int nt = 0; nt < 4; ++nt) {
                    #pragma unroll
                    for (int r = 0; r < 4; ++r) {
                        float sv = sa[rb][nt][r];
                        if (dodiag) {
                            const int keyg = kb + nt * 16 + quad * 4 + r;
                            if (keyg > qr) sv = -INFINITY;
                        }
                        p[nt][r] = sv;
                    }
                }
                float mv;
                {
                    const float t0 = fmaxf(fmaxf(p[0][0], p[0][1]), fmaxf(p[0][2], p[0][3]));
                    const float t1 = fmaxf(fmaxf(p[1][0], p[1][1]), fmaxf(p[1][2], p[1][3]));
                    const float t2 = fmaxf(fmaxf(p[2][0], p[2][1]), fmaxf(p[2][2], p[2][3]));
                    const float t3 = fmaxf(fmaxf(p[3][0], p[3][1]), fmaxf(p[3][2], p[3][3]));
                    mv = fmaxf(fmaxf(t0, t1), fmaxf(t2, t3));
                    mv = fmaxf(mv, __shfl_xor(mv, 16));
                    mv = fmaxf(mv, __shfl_xor(mv, 32));
                }
                if (__any(mv - m_q[rb] > THR2)) {
                    const float mnew = fmaxf(m_q[rb], mv);
                    const float al = exp2_fast(m_q[rb] - mnew);   // -inf start -> al=0, o already 0
                    m_q[rb] = mnew;
                    l_q[rb] *= al;
                    float alo[4];
                    #pragma unroll
                    for (int r = 0; r < 4; ++r)
                        alo[r] = __shfl(al, quad * 20 + r);       // alpha of o-row quad*4+r
                    #pragma unroll
                    for (int dn = 0; dn < 8; ++dn)
                        #pragma unroll
                        for (int r = 0; r < 4; ++r) o[rb][dn][r] *= alo[r];
                }
                #pragma unroll
                for (int nt = 0; nt < 4; ++nt) {
                    const float e0 = exp2_fast(p[nt][0] - m_q[rb]);
                    const float e1 = exp2_fast(p[nt][1] - m_q[rb]);
                    const float e2 = exp2_fast(p[nt][2] - m_q[rb]);
                    const float e3 = exp2_fast(p[nt][3] - m_q[rb]);
                    l_q[rb] += (e0 + e1) + (e2 + e3);
                    uint2 w;
                    w.x = cvt_pk_bf16(e0, e1);
                    w.y = cvt_pk_bf16(e2, e3);
                    *(uint2*)(pw[nt] + rb * 4096) = w;
                }
            }

            // same-wave LDS RAW: drain P writes, read PV A-frags (rows are wave-private)
            asm volatile("s_waitcnt lgkmcnt(0)" ::: "memory");
            short8 pf[2][2];
            pf[0][0] = *(const short8*)pr0;
            pf[0][1] = *(const short8*)pr1;
            pf[1][0] = *(const short8*)(pr0 + 4096);
            pf[1][1] = *(const short8*)(pr1 + 4096);

            // ---- O += P V; each V frag read once, feeds both sub-blocks ----
            __builtin_amdgcn_s_setprio(1);
            #pragma unroll
            for (int c2 = 0; c2 < 2; ++c2) {
                #pragma unroll
                for (int dn = 0; dn < 8; ++dn) {
                    const short8 vv = *(const short8*)(Vl + (c2 * 8 + dn) * 512 + lane * 8);
                    o[0][dn] = __builtin_amdgcn_mfma_f32_16x16x32_bf16(pf[0][c2], vv, o[0][dn], 0, 0, 0);
                    o[1][dn] = __builtin_amdgcn_mfma_f32_16x16x32_bf16(pf[1][c2], vv, o[1][dn], 0, 0, 0);
                }
            }
            __builtin_amdgcn_s_setprio(0);

            __syncthreads();   // next tile staged (vmcnt 0 at barrier), buf[cur] free
        }

        // ---- epilogue: per rb, l reduce + per-wave fp32 slab (aliases bufs) ----
        float* Ot = (float*)smem + wave * 2048;   // per-wave [16][128] fp32 (8 KB)
        #pragma unroll
        for (int rb = 0; rb < 2; ++rb) {
            float ls = l_q[rb];
            ls += __shfl_xor(ls, 16);
            ls += __shfl_xor(ls, 32);
            const float inv_q = 1.f / ls;
            float inv[4];
            #pragma unroll
            for (int r = 0; r < 4; ++r)
                inv[r] = __shfl(inv_q, quad * 20 + r);
            #pragma unroll
            for (int dn = 0; dn < 8; ++dn)
                #pragma unroll
                for (int r = 0; r < 4; ++r)
                    Ot[(quad * 4 + r) * 128 + dn * 16 + m16] = o[rb][dn][r] * inv[r];
            asm volatile("s_waitcnt lgkmcnt(0)" ::: "memory");
            float* og = out + (size_t)(b * S_ + qbase + rb * 64 + wave * 16) * (H_ * D_) + h * D_;
            #pragma unroll
            for (int i = 0; i < 8; ++i) {
                const int row = (lane >> 5) + i * 2;
                const int col = (lane & 31) * 4;
                *(float4*)(og + (size_t)row * (H_ * D_) + col) = *(const float4*)(Ot + row * 128 + col);
            }
            // per-wave in-order LDS: rb=1 slab writes queue after rb=0 slab reads (WAR safe)
        }
    }
}

extern "C" void kernel_launch(void* const* d_in, const int* in_sizes, int n_in,
                              void* d_out, int out_size, void* d_ws, size_t ws_size,
                              hipStream_t stream) {
    const float* q = (const float*)d_in[0];
    const float* k = (const float*)d_in[1];
    const float* v = (const float*)d_in[2];
    float* out = (float*)d_out;

    unsigned short* kfb = (unsigned short*)d_ws;                                  // 8 MB
    unsigned short* vfb = (unsigned short*)d_ws + (size_t)B_ * KVH_ * S_ * D_;    // 8 MB

    prep_kernel<<<dim3(NT_, B_ * KVH_), dim3(256), 0, stream>>>(k, v, kfb, vfb);
    fa11_kernel<<<dim3(8, B_ * H_), dim3(256), 0, stream>>>(q, kfb, vfb, out);
}